// Round 3
// baseline (95.010 us; speedup 1.0000x reference)
//
#include <hip/hip_runtime.h>
#include <hip/hip_bf16.h>

// ---------------------------------------------------------------------------
// advantage = -0.5 * || T(flat) @ (actions-best) ||^2 per row, where
// flat = logits @ W^T + b, T = lower-tri scatter with squared diagonal.
// Round 3: BM=64, 256 threads (4 waves), 2 blocks/CU (LDS 76KB), A staged
// bf16 frag-linear via reg-path (2-step prefetch), W via global_load_lds dbuf.
// ---------------------------------------------------------------------------

typedef __attribute__((ext_vector_type(8))) __bf16 bf16x8;
typedef __attribute__((ext_vector_type(4))) float f32x4;

#define AS1 __attribute__((address_space(1)))
#define AS3 __attribute__((address_space(3)))

__device__ __forceinline__ unsigned short f2b(float x) {
  unsigned u = __builtin_bit_cast(unsigned, x);
  u += 0x7fffu + ((u >> 16) & 1u);     // RNE; inputs are finite
  return (unsigned short)(u >> 16);
}
__device__ __forceinline__ float b2f(unsigned short h) {
  unsigned u = ((unsigned)h) << 16;
  return __builtin_bit_cast(float, u);
}

#define NFRAG 34                     // 544 padded cols / 16
#define WK_BYTES (NFRAG * 1024)      // 34816 B per BK=32 step (bf16 frag-linear)
#define AOFF (2 * WK_BYTES)          // 69632: A buffers (2 x 4096, bf16 frag-linear)
#define SMEM_BYTES (AOFF + 2 * 4096) // 77824 -> 2 blocks/CU
#define FLAT_STRIDE 532
#define DIFF_OFF (64 * FLAT_STRIDE * 2)   // 68096 (+8192 = 76288 <= 77824)

// --- prep: W [528][512] f32 -> fragment-linear bf16, padded to 544 rows ----
// WP[k16][nf][lane][j] = bf16(W[nf*16+(lane&15)][k16*32+(lane>>4)*8+j])
__global__ void prep_wp(const float* __restrict__ W, unsigned short* __restrict__ WP) {
  int t = blockIdx.x * 256 + threadIdx.x;   // [0, 34816)
  int lane = t & 63;
  int u = t >> 6;                            // [0, 544)
  int nf = u % NFRAG;
  int k16 = u / NFRAG;                       // [0, 16)
  int n = nf * 16 + (lane & 15);
  int k0 = k16 * 32 + (lane >> 4) * 8;
  unsigned short h[8];
  if (n < 528) {
    const float* src = W + (size_t)n * 512 + k0;
#pragma unroll
    for (int j = 0; j < 8; ++j) h[j] = f2b(src[j]);
  } else {
#pragma unroll
    for (int j = 0; j < 8; ++j) h[j] = 0;
  }
  uint4 p;
  p.x = (unsigned)h[0] | ((unsigned)h[1] << 16);
  p.y = (unsigned)h[2] | ((unsigned)h[3] << 16);
  p.z = (unsigned)h[4] | ((unsigned)h[5] << 16);
  p.w = (unsigned)h[6] | ((unsigned)h[7] << 16);
  *(uint4*)(WP + (size_t)t * 8) = p;
}

// --- main fused kernel ------------------------------------------------------
__global__ void __launch_bounds__(256, 2)
adv_kernel(const float* __restrict__ logits,
           const float* __restrict__ best,
           const float* __restrict__ actions,
           const float* __restrict__ bvec,
           const unsigned short* __restrict__ WP,
           float* __restrict__ out) {
  extern __shared__ char smem[];
  const int tid = threadIdx.x;
  const int l   = tid & 63;
  const int wid = tid >> 6;                // 4 waves = 4 N-cols (1 M-row)
  const int lr  = l & 15;
  const int lg  = l >> 4;
  const int start = wid * 8 + (wid > 0 ? 1 : 0);  // 0,9,17,25 (frags 17,25 dup)
  const int brow = blockIdx.x * 64;

  f32x4 acc[4][9];
  {
    f32x4 zero = {0.f, 0.f, 0.f, 0.f};
#pragma unroll
    for (int m = 0; m < 4; ++m)
#pragma unroll
      for (int n = 0; n < 9; ++n) acc[m][n] = zero;
  }

  // A staging: thread tid owns frag-slot (m = wid, lane = l):
  //   bf16(logits[brow + wid*16 + lr][ks*32 + lg*8 + j]) -> Abuf + tid*16 + j*2
  const float* agbase = logits + (size_t)(brow + wid * 16 + lr) * 512 + lg * 8;

#define STAGE_W(dst, ks)                                                        \
  {                                                                             \
    const char* sW = (const char*)WP + (size_t)(ks) * WK_BYTES;                 \
    _Pragma("unroll")                                                           \
    for (int q = 0; q < 8; ++q) {                                               \
      int off = (q * 4 + wid) * 1024;                                           \
      __builtin_amdgcn_global_load_lds((AS1 unsigned int*)(sW + off + l * 16),  \
          (AS3 unsigned int*)((dst) + off), 16, 0, 0);                          \
    }                                                                           \
    if (wid < 2) {                                                              \
      int off = (32 + wid) * 1024;                                              \
      __builtin_amdgcn_global_load_lds((AS1 unsigned int*)(sW + off + l * 16),  \
          (AS3 unsigned int*)((dst) + off), 16, 0, 0);                          \
    }                                                                           \
  }

#define LOAD_A(dst, ks)                                                         \
  {                                                                             \
    const float* g = agbase + (ks) * 32;                                        \
    (dst)[0] = *(const float4*)(g);                                             \
    (dst)[1] = *(const float4*)(g + 4);                                         \
  }

#define WRITE_A(buf_idx, src)                                                   \
  {                                                                             \
    uint4 p;                                                                    \
    p.x = f2b((src)[0].x) | ((unsigned)f2b((src)[0].y) << 16);                  \
    p.y = f2b((src)[0].z) | ((unsigned)f2b((src)[0].w) << 16);                  \
    p.z = f2b((src)[1].x) | ((unsigned)f2b((src)[1].y) << 16);                  \
    p.w = f2b((src)[1].z) | ((unsigned)f2b((src)[1].w) << 16);                  \
    *(uint4*)(smem + AOFF + (buf_idx) * 4096 + tid * 16) = p;                   \
  }

  float4 pf[2][2];          // 2-step A prefetch (fully unrolled -> static idx)
  LOAD_A(pf[0], 0)
  LOAD_A(pf[1], 1)
  STAGE_W(smem, 0)
  WRITE_A(0, pf[0])
  __syncthreads();

#pragma unroll
  for (int t = 0; t < 16; ++t) {
    char* wb = smem + (t & 1) * WK_BYTES;
    const char* ab = smem + AOFF + (t & 1) * 4096;
    if (t < 15) STAGE_W(smem + ((t + 1) & 1) * WK_BYTES, t + 1)
    if (t < 14) LOAD_A(pf[t & 1], t + 2)
    bf16x8 a[4];
#pragma unroll
    for (int m = 0; m < 4; ++m)
      a[m] = *(const bf16x8*)(ab + m * 1024 + l * 16);
#pragma unroll
    for (int n = 0; n < 9; ++n) {
      bf16x8 bfr = *(const bf16x8*)(wb + (start + n) * 1024 + l * 16);
#pragma unroll
      for (int m = 0; m < 4; ++m)
        acc[m][n] = __builtin_amdgcn_mfma_f32_16x16x32_bf16(a[m], bfr, acc[m][n], 0, 0, 0);
    }
    if (t < 15) WRITE_A((t + 1) & 1, pf[(t + 1) & 1])
    __syncthreads();
  }

  // epilogue: flat(+bias) -> bf16 LDS [64][532]; diff -> f32 LDS (swizzled)
  unsigned short* fl = (unsigned short*)smem;
#pragma unroll
  for (int n = 0; n < 9; ++n) {
    int nf = start + n;
    if (nf >= 33) continue;             // frag 33 is pure padding
    int f = nf * 16 + lr;               // < 528
    float bb = bvec[f];
#pragma unroll
    for (int m = 0; m < 4; ++m)
#pragma unroll
      for (int r = 0; r < 4; ++r) {
        int row = m * 16 + lg * 4 + r;  // C/D: col=lane&15, row=(lane>>4)*4+reg
        fl[row * FLAT_STRIDE + f] = f2b(acc[m][n][r] + bb);
      }
  }
  {
    float* dl = (float*)(smem + DIFF_OFF);       // [64][32] f32, XOR-swizzled
    int row = tid >> 2;
    int j0  = (tid & 3) << 3;
    const float* ap = actions + (size_t)(brow + row) * 32 + j0;
    const float* bp = best    + (size_t)(brow + row) * 32 + j0;
    float4 a0 = *(const float4*)(ap);
    float4 a1 = *(const float4*)(ap + 4);
    float4 b0 = *(const float4*)(bp);
    float4 b1 = *(const float4*)(bp + 4);
    float d[8] = {a0.x - b0.x, a0.y - b0.y, a0.z - b0.z, a0.w - b0.w,
                  a1.x - b1.x, a1.y - b1.y, a1.z - b1.z, a1.w - b1.w};
    int rs = row & 31;
#pragma unroll
    for (int q = 0; q < 8; ++q)
      dl[row * 32 + ((j0 + q) ^ rs)] = d[q];
  }
  __syncthreads();

  // per-row: vec[i] = sum_{j<i} flat[tri+j]*diff[j] + flat[tri+i]^2*diff[i]
  // 4 threads/row, i = (tid&3) + 4*ii (balanced); reduce with shfl_xor.
  {
    int it  = tid & 3;
    int row = tid >> 2;
    const unsigned short* flr = fl + row * FLAT_STRIDE;
    const float* dlr = (const float*)(smem + DIFF_OFF) + row * 32;
    int rs = row & 31;
    float ssum = 0.f;
#pragma unroll
    for (int ii = 0; ii < 8; ++ii) {
      int i = it + ii * 4;
      int tri = (i * (i + 1)) >> 1;
      float vec = 0.f;
      for (int j = 0; j < i; ++j)
        vec += b2f(flr[tri + j]) * dlr[j ^ rs];
      float dv = b2f(flr[tri + i]);
      vec += dv * dv * dlr[i ^ rs];
      ssum += vec * vec;
    }
    ssum += __shfl_xor(ssum, 1);
    ssum += __shfl_xor(ssum, 2);
    if (it == 0) out[brow + row] = -0.5f * ssum;
  }
}

extern "C" void kernel_launch(void* const* d_in, const int* in_sizes, int n_in,
                              void* d_out, int out_size, void* d_ws, size_t ws_size,
                              hipStream_t stream) {
  const float* logits  = (const float*)d_in[0];
  const float* best    = (const float*)d_in[1];
  const float* actions = (const float*)d_in[2];
  const float* W       = (const float*)d_in[3];
  const float* bvec    = (const float*)d_in[4];
  float* out = (float*)d_out;
  unsigned short* WP = (unsigned short*)d_ws;   // needs 557056 B

  hipLaunchKernelGGL(prep_wp, dim3(136), dim3(256), 0, stream, W, WP);
  int M = in_sizes[0] / 512;                    // 65536 rows
  hipLaunchKernelGGL(adv_kernel, dim3(M / 64), dim3(256), SMEM_BYTES, stream,
                     logits, best, actions, bvec, WP, out);
}

// Round 4
// 70.686 us; speedup vs baseline: 1.3441x; 1.3441x over previous
//
#include <hip/hip_runtime.h>
#include <hip/hip_bf16.h>

// ---------------------------------------------------------------------------
// advantage = -0.5 * || T(flat) @ (actions-best) ||^2 per row, where
// flat = logits @ W^T + b, T = lower-tri scatter with squared diagonal.
// Round 4: BM=64, 4 waves, 2 blocks/CU, unroll-2 K-loop (no spills), bf16
// frag-linear A via reg path, vectorized compile-time-indexed epilogue.
// ---------------------------------------------------------------------------

typedef __attribute__((ext_vector_type(8))) __bf16 bf16x8;
typedef __attribute__((ext_vector_type(4))) float f32x4;

#define AS1 __attribute__((address_space(1)))
#define AS3 __attribute__((address_space(3)))

__device__ __forceinline__ unsigned short f2b(float x) {
  unsigned u = __builtin_bit_cast(unsigned, x);
  u += 0x7fffu + ((u >> 16) & 1u);     // RNE; inputs are finite
  return (unsigned short)(u >> 16);
}
__device__ __forceinline__ float b2f(unsigned short h) {
  unsigned u = ((unsigned)h) << 16;
  return __builtin_bit_cast(float, u);
}

#define NFRAG 34                       // 544 padded cols / 16
#define WK_BYTES (NFRAG * 1024)        // 34816 B per BK=32 step
#define AOFF (2 * WK_BYTES)            // 69632
#define ABUF 4096                      // A bf16 frag-image per step
#define FL_STRIDE 1216                 // flat row stride (bytes); 64*1216=77824
#define PL_OFF (64 * FL_STRIDE)        // 77824
#define SMEM_BYTES (PL_OFF + 1024)     // 78848 -> 2 blocks/CU (157696 <= 160K)

// --- prep: W [528][512] f32 -> fragment-linear bf16, padded to 544 rows ----
// WP[k16][nf][lane][j] = bf16(W[nf*16+(lane&15)][k16*32+(lane>>4)*8+j])
__global__ void prep_wp(const float* __restrict__ W, unsigned short* __restrict__ WP) {
  int t = blockIdx.x * 256 + threadIdx.x;   // [0, 34816)
  int lane = t & 63;
  int u = t >> 6;                            // [0, 544)
  int nf = u % NFRAG;
  int k16 = u / NFRAG;                       // [0, 16)
  int n = nf * 16 + (lane & 15);
  int k0 = k16 * 32 + (lane >> 4) * 8;
  unsigned short h[8];
  if (n < 528) {
    const float* src = W + (size_t)n * 512 + k0;
#pragma unroll
    for (int j = 0; j < 8; ++j) h[j] = f2b(src[j]);
  } else {
#pragma unroll
    for (int j = 0; j < 8; ++j) h[j] = 0;
  }
  uint4 p;
  p.x = (unsigned)h[0] | ((unsigned)h[1] << 16);
  p.y = (unsigned)h[2] | ((unsigned)h[3] << 16);
  p.z = (unsigned)h[4] | ((unsigned)h[5] << 16);
  p.w = (unsigned)h[6] | ((unsigned)h[7] << 16);
  *(uint4*)(WP + (size_t)t * 8) = p;
}

// --- epilogue worker: one lane per row, i in {IT, IT+4, ..., IT+28} --------
template <int IT>
__device__ __forceinline__ float epi_partial(const char* smem,
                                             const float* __restrict__ actions,
                                             const float* __restrict__ best,
                                             int brow, int l) {
  float d[32];
  const float* ap = actions + (size_t)(brow + l) * 32;
  const float* bp = best + (size_t)(brow + l) * 32;
#pragma unroll
  for (int q = 0; q < 8; ++q) {
    float4 av = *(const float4*)(ap + q * 4);
    float4 bv = *(const float4*)(bp + q * 4);
    d[q * 4 + 0] = av.x - bv.x;
    d[q * 4 + 1] = av.y - bv.y;
    d[q * 4 + 2] = av.z - bv.z;
    d[q * 4 + 3] = av.w - bv.w;
  }
  const char* frow = smem + l * FL_STRIDE;
  const int swz = (l & 7) << 4;
  float ssum = 0.f;
#pragma unroll
  for (int ii = 0; ii < 8; ++ii) {
    const int i = IT + ii * 4;          // compile-time
    const int tri2 = i * (i + 1);       // byte offset of row-i start in flat
    const int s0 = tri2 >> 4;
    const int s1 = (tri2 + 2 * i) >> 4;
    float vec = 0.f;
#pragma unroll
    for (int s = s0; s <= s1; ++s) {
      uint4 w = *(const uint4*)(frow + ((s * 16) ^ swz));
      const unsigned* wp = (const unsigned*)&w;
#pragma unroll
      for (int e = 0; e < 8; ++e) {
        const int j = s * 8 + e - (tri2 >> 1);   // compile-time
        if (j < 0 || j > i) continue;
        unsigned short h = (e & 1) ? (unsigned short)(wp[e >> 1] >> 16)
                                   : (unsigned short)(wp[e >> 1] & 0xffffu);
        float v = b2f(h);
        if (j == i) vec += v * v * d[i];         // squared diagonal
        else        vec += v * d[j];
      }
    }
    ssum += vec * vec;
  }
  return ssum;
}

// --- main fused kernel ------------------------------------------------------
__global__ void __launch_bounds__(256, 2)
adv_kernel(const float* __restrict__ logits,
           const float* __restrict__ best,
           const float* __restrict__ actions,
           const float* __restrict__ bvec,
           const unsigned short* __restrict__ WP,
           float* __restrict__ out) {
  extern __shared__ char smem[];
  const int tid = threadIdx.x;
  const int l   = tid & 63;
  const int wid = tid >> 6;                // 4 waves = 4 N-cols (1 M-row)
  const int lr  = l & 15;
  const int lg  = l >> 4;
  const int start = wid * 8 + (wid > 0 ? 1 : 0);  // 0,9,17,25 (17,25 dup'd)
  const int brow = blockIdx.x * 64;

  f32x4 acc[4][9];
  {
    f32x4 zero = {0.f, 0.f, 0.f, 0.f};
#pragma unroll
    for (int m = 0; m < 4; ++m)
#pragma unroll
      for (int n = 0; n < 9; ++n) acc[m][n] = zero;
  }

  // A staging: thread stages frag m = wid, lane l:
  //   bf16(logits[brow+wid*16+lr][ks*32 + lg*8 + 0..7]) -> abuf + tid*16
  const float* agbase = logits + (size_t)(brow + wid * 16 + lr) * 512 + lg * 8;

#define STAGE_W(dst, ks)                                                        \
  {                                                                             \
    const char* sW = (const char*)WP + (size_t)(ks) * WK_BYTES;                 \
    _Pragma("unroll")                                                           \
    for (int q = 0; q < 8; ++q) {                                               \
      int off = (q * 4 + wid) * 1024;                                           \
      __builtin_amdgcn_global_load_lds((AS1 unsigned int*)(sW + off + l * 16),  \
          (AS3 unsigned int*)((dst) + off), 16, 0, 0);                          \
    }                                                                           \
    if (wid < 2) {                                                              \
      int off = (32 + wid) * 1024;                                              \
      __builtin_amdgcn_global_load_lds((AS1 unsigned int*)(sW + off + l * 16),  \
          (AS3 unsigned int*)((dst) + off), 16, 0, 0);                          \
    }                                                                           \
  }

#define LOAD_A(dst, ks)                                                         \
  {                                                                             \
    const float* g = agbase + (ks) * 32;                                        \
    (dst)[0] = *(const float4*)(g);                                             \
    (dst)[1] = *(const float4*)(g + 4);                                         \
  }

#define WRITE_A(buf_idx, src)                                                   \
  {                                                                             \
    uint4 p;                                                                    \
    p.x = f2b((src)[0].x) | ((unsigned)f2b((src)[0].y) << 16);                  \
    p.y = f2b((src)[0].z) | ((unsigned)f2b((src)[0].w) << 16);                  \
    p.z = f2b((src)[1].x) | ((unsigned)f2b((src)[1].y) << 16);                  \
    p.w = f2b((src)[1].z) | ((unsigned)f2b((src)[1].w) << 16);                  \
    *(uint4*)(smem + AOFF + (buf_idx) * ABUF + tid * 16) = p;                   \
  }

#define COMPUTE(p)                                                              \
  {                                                                             \
    const char* ab = smem + AOFF + (p) * ABUF;                                  \
    const char* wb = smem + (p) * WK_BYTES;                                     \
    bf16x8 a[4];                                                                \
    _Pragma("unroll")                                                           \
    for (int m = 0; m < 4; ++m)                                                 \
      a[m] = *(const bf16x8*)(ab + m * 1024 + l * 16);                          \
    _Pragma("unroll")                                                           \
    for (int n = 0; n < 9; ++n) {                                               \
      bf16x8 w = *(const bf16x8*)(wb + (start + n) * 1024 + l * 16);            \
      _Pragma("unroll")                                                         \
      for (int m = 0; m < 4; ++m)                                               \
        acc[m][n] = __builtin_amdgcn_mfma_f32_16x16x32_bf16(a[m], w, acc[m][n], 0, 0, 0); \
    }                                                                           \
  }

  float4 pf0[2], pf1[2];                 // dual single-step prefetch (16 regs)
  LOAD_A(pf0, 0)
  LOAD_A(pf1, 1)
  STAGE_W(smem, 0)
  WRITE_A(0, pf0)
  __syncthreads();

  for (int t2 = 0; t2 < 16; t2 += 2) {
    // even step t2 (parity 0)
    if (t2 < 15) STAGE_W(smem + WK_BYTES, t2 + 1)
    if (t2 < 14) LOAD_A(pf0, t2 + 2)     // pf0 consumed two steps ago
    COMPUTE(0)
    if (t2 < 15) WRITE_A(1, pf1)         // step t2+1 data
    __syncthreads();
    // odd step t2+1 (parity 1)
    {
      int t = t2 + 1;
      if (t < 15) STAGE_W(smem, t + 1)
      if (t < 14) LOAD_A(pf1, t + 2)
      COMPUTE(1)
      if (t < 15) WRITE_A(0, pf0)
      __syncthreads();
    }
  }

  // ---- epilogue: flat(+bias) -> swizzled bf16 LDS [64][FL_STRIDE] ----------
#pragma unroll
  for (int n = 0; n < 9; ++n) {
    int nf = start + n;
    if (nf >= 33) continue;              // frag 33 is pure padding
    int f = nf * 16 + lr;                // < 528
    float bb = bvec[f];
#pragma unroll
    for (int m = 0; m < 4; ++m)
#pragma unroll
      for (int r = 0; r < 4; ++r) {
        int row = m * 16 + lg * 4 + r;   // C/D: col=lane&15, row=(lane>>4)*4+reg
        int byte = row * FL_STRIDE + ((f * 2) ^ ((row & 7) << 4));
        *(unsigned short*)(smem + byte) = f2b(acc[m][n][r] + bb);
      }
  }
  __syncthreads();

  // ---- tril matvec: lane = row, wave wid covers i in {wid, wid+4, ...} -----
  float ssum;
  switch (wid) {
    case 0:  ssum = epi_partial<0>(smem, actions, best, brow, l); break;
    case 1:  ssum = epi_partial<1>(smem, actions, best, brow, l); break;
    case 2:  ssum = epi_partial<2>(smem, actions, best, brow, l); break;
    default: ssum = epi_partial<3>(smem, actions, best, brow, l); break;
  }
  ((float*)(smem + PL_OFF))[l * 4 + wid] = ssum;
  __syncthreads();
  if (tid < 64) {
    f32x4 p4 = *(const f32x4*)(smem + PL_OFF + tid * 16);
    out[brow + tid] = -0.5f * (p4[0] + p4[1] + p4[2] + p4[3]);
  }
}

extern "C" void kernel_launch(void* const* d_in, const int* in_sizes, int n_in,
                              void* d_out, int out_size, void* d_ws, size_t ws_size,
                              hipStream_t stream) {
  const float* logits  = (const float*)d_in[0];
  const float* best    = (const float*)d_in[1];
  const float* actions = (const float*)d_in[2];
  const float* W       = (const float*)d_in[3];
  const float* bvec    = (const float*)d_in[4];
  float* out = (float*)d_out;
  unsigned short* WP = (unsigned short*)d_ws;   // needs 557056 B

  hipLaunchKernelGGL(prep_wp, dim3(136), dim3(256), 0, stream, W, WP);
  int M = in_sizes[0] / 512;                    // 65536 rows
  hipLaunchKernelGGL(adv_kernel, dim3(M / 64), dim3(256), SMEM_BYTES, stream,
                     logits, best, actions, bvec, WP, out);
}